// Round 1
// 533.720 us; speedup vs baseline: 1.5038x; 1.5038x over previous
//
#include <hip/hip_runtime.h>
#include <stdint.h>

#define NROW 100000
#define DDIM 512
#define NPAIR 528
#define PK 544            // pairs padded to 17*32
#define BR 32             // rows per fused block
#define NBLK 3125         // 100000 / 32 exactly (no edge guards needed)
#define GAMMA 0.01f
#define ALPHA 1.0f
#define TOLR 1e-6f
#define GUESS 0.999f

using f32x4  = __attribute__((ext_vector_type(4))) float;
using s16x8  = __attribute__((ext_vector_type(8))) short;
using us16x4 = __attribute__((ext_vector_type(4))) unsigned short;
typedef unsigned short ushort_t;
typedef unsigned int   uint_t;

// ---- ws byte offsets ----
#define WS_XMUU   0          // 32 f32
#define WS_XCU    128        // 32 f32
#define WS_MUN    256        // 1 f32
#define WS_CHANGE 512        // 512 f32
#define WS_UB     4096       // Ub2: 3 tiles * 16 ks * 512 = 24576 ushorts (49152 B), fragment-order
#define WS_VB     53248      // Vb2: 32 tiles * 17 ks * 512 = 278528 ushorts (557056 B), fragment-order
#define WS_IU     610304     // 544 ushorts: (a<<8)|b triu indices

// ---- shared mem layout (40064 B total -> 3 blocks/CU with headroom) ----
#define ZB_STR   520         // ushorts; Z tile stride (1040 B, 16B aligned)
#define HB_STR   552         // ushorts; H tile stride (1104 B, 16B aligned)
#define SM_ZU    35328       // 32*34 f32 (cols 0..31 ZU->coord, 32 z.zmu, 33 ss->ksc)
#define SM_CIDX  39680       // 32 int
#define SM_XMU   39808       // 32 f32
#define SM_XCU   39936       // 32 f32
#define SM_TOTAL 40064

__device__ __forceinline__ ushort_t f2bf(float x) {
    uint_t u = __builtin_bit_cast(uint_t, x);
    u += 0x7fffu + ((u >> 16) & 1u);          // RNE
    return (ushort_t)(u >> 16);
}

// ---------------- kernel A: scalars + fragment-order bf16 pre-pack ----------------
__global__ __launch_bounds__(256) void kernelA(const float* __restrict__ U,
                                               const float* __restrict__ V,
                                               const float* __restrict__ zmu,
                                               const float* __restrict__ xc,
                                               char* __restrict__ ws) {
    int t = threadIdx.x;
    if (blockIdx.x == 0) {
        __shared__ float redMu[8][32], redC[8][32], redN[8];
        __shared__ float w_s[32];
        int k = t & 31, g = t >> 5;
        float smu = 0.f, sc = 0.f, sn = 0.f;
        for (int d = g * 64; d < g * 64 + 64; ++d) {
            float u = U[d * 32 + k];
            float zm = zmu[d];
            smu += zm * u;
            sc  += xc[d] * u;
            if (k == 0) sn += zm * zm;
        }
        redMu[g][k] = smu; redC[g][k] = sc;
        if (k == 0) redN[g] = sn;
        __syncthreads();
        float* xmuU = (float*)(ws + WS_XMUU);
        float* xcU  = (float*)(ws + WS_XCU);
        if (t < 32) {
            float a = 0.f, b = 0.f;
            for (int g2 = 0; g2 < 8; ++g2) { a += redMu[g2][t]; b += redC[g2][t]; }
            xmuU[t] = a; xcU[t] = b; w_s[t] = b - a;
        }
        if (t == 0) {
            float m = 0.f;
            for (int g2 = 0; g2 < 8; ++g2) m += redN[g2];
            *(float*)(ws + WS_MUN) = m;
        }
        __syncthreads();
        float* change = (float*)(ws + WS_CHANGE);
        for (int d = t; d < DDIM; d += 256) {
            float s = 0.f;
            #pragma unroll
            for (int k2 = 0; k2 < 32; ++k2) s += U[d * 32 + k2] * w_s[k2];
            change[d] = xc[d] - zmu[d] - s;
        }
        // triu_indices table, packed (a<<8)|b
        ushort_t* iuT = (ushort_t*)(ws + WS_IU);
        for (int p = t; p < PK; p += 256) {
            int a = 0;
            while (a < 31) { int nxt = 32 * (a + 1) - (a + 1) * a / 2; if (p >= nxt) a++; else break; }
            int st = 32 * a - a * (a - 1) / 2;
            int b = a + (p - st);
            if (p >= NPAIR) { a = 31; b = 31; }
            iuT[p] = (ushort_t)((a << 8) | (b & 255));
        }
    } else {
        int blk = blockIdx.x - 1;  // 0..127
        // Vb2 fragment order: idx = (tile*17 + ks)*512 + (m*4+quad)*8 + e
        //   holds V[col = tile*16+m][pair = ks*32+quad*8+e]  (pad pairs -> 0)
        ushort_t* Vb2 = (ushort_t*)(ws + WS_VB);
        for (int i = blk * 256 + t; i < 32 * 17 * 512; i += 128 * 256) {
            int tile = i / 8704;              // 17*512
            int r1 = i - tile * 8704;
            int ks = r1 >> 9, r2 = r1 & 511;
            int mm = r2 >> 5, qq = (r2 >> 3) & 3, e = r2 & 7;
            int c = tile * 16 + mm;
            int p = ks * 32 + qq * 8 + e;
            float v = (p < NPAIR) ? V[c * NPAIR + p] : 0.f;
            Vb2[i] = f2bf(v);
        }
        // Ub2 fragment order: idx = (ct*16 + ks)*512 + (m*4+quad)*8 + e
        //   holds Uext[d = ks*32+quad*8+e][col = ct*16+mm]; col 32 = zmu, 33..47 = 0
        ushort_t* Ub2 = (ushort_t*)(ws + WS_UB);
        for (int i = blk * 256 + t; i < 3 * 16 * 512; i += 128 * 256) {
            int ct = i >> 13, r1 = i & 8191;
            int ks = r1 >> 9, r2 = r1 & 511;
            int mm = r2 >> 5, qq = (r2 >> 3) & 3, e = r2 & 7;
            int c = ct * 16 + mm, d = ks * 32 + qq * 8 + e;
            float v = (c < 32) ? U[d * 32 + c] : ((c == 32) ? zmu[d] : 0.f);
            Ub2[i] = f2bf(v);
        }
    }
}

// ---------------- fused kernel: stage -> ZU -> norms -> solve -> H -> GEMM -> epilogue ----------------
__global__ __launch_bounds__(256, 3) void kernelF(const float* __restrict__ Z,
                                                  const int* __restrict__ ci,
                                                  const char* __restrict__ ws,
                                                  float* __restrict__ out) {
    __shared__ __align__(16) char smem[SM_TOTAL];
    ushort_t* zb = (ushort_t*)smem;                 // [32][ZB_STR] bf16 Z tile
    ushort_t* hb = (ushort_t*)smem;                 // [32][HB_STR] bf16 H tile (overwrites zb)
    float* zu    = (float*)(smem + SM_ZU);          // [32][34]
    int*   cidx  = (int*)(smem + SM_CIDX);
    float* xmu_s = (float*)(smem + SM_XMU);
    float* xcu_s = (float*)(smem + SM_XCU);

    int t = threadIdx.x;
    int rowBase = blockIdx.x * BR;

    if (t < 32) cidx[t] = ci[rowBase + t];
    else if (t < 64)  xmu_s[t - 32] = ((const float*)(ws + WS_XMUU))[t - 32];
    else if (t < 96)  xcu_s[t - 64] = ((const float*)(ws + WS_XCU))[t - 64];

    // ---- phase 1: stage Z tile f32 -> bf16, loads batched 8-deep ----
    {
        #pragma unroll
        for (int half = 0; half < 2; ++half) {
            float4 v[8];
            #pragma unroll
            for (int j = 0; j < 8; ++j) {
                int i = t + (half * 8 + j) * 256;
                int row = i >> 7, c4 = i & 127;
                v[j] = ((const float4*)(Z + (size_t)ci[rowBase + row] * DDIM))[c4];
            }
            #pragma unroll
            for (int j = 0; j < 8; ++j) {
                int i = t + (half * 8 + j) * 256;
                int row = i >> 7, c4 = i & 127;
                *(us16x4*)&zb[row * ZB_STR + c4 * 4] =
                    (us16x4){f2bf(v[j].x), f2bf(v[j].y), f2bf(v[j].z), f2bf(v[j].w)};
            }
        }
    }
    __syncthreads();

    int wv = t >> 6, lane = t & 63, m = lane & 15, quad = lane >> 4;
    int laneoff = (m * 4 + quad) * 8;

    // ---- phase 2a: ZU_ext GEMM (wave w: row-tile w>>1, col-tile w&1; even waves also col 32) ----
    {
        int rt = wv >> 1, ctA = wv & 1;
        const ushort_t* Ub2 = (const ushort_t*)(ws + WS_UB);
        f32x4 accA = {0, 0, 0, 0}, acc2 = {0, 0, 0, 0};
        #pragma unroll
        for (int ks = 0; ks < 16; ++ks) {
            s16x8 a  = *(const s16x8*)&zb[(rt * 16 + m) * ZB_STR + ks * 32 + quad * 8];
            s16x8 bA = *(const s16x8*)&Ub2[(ctA * 16 + ks) * 512 + laneoff];
            accA = __builtin_amdgcn_mfma_f32_16x16x32_bf16(a, bA, accA, 0, 0, 0);
            if (ctA == 0) {
                s16x8 b2 = *(const s16x8*)&Ub2[(32 + ks) * 512 + laneoff];
                acc2 = __builtin_amdgcn_mfma_f32_16x16x32_bf16(a, b2, acc2, 0, 0, 0);
            }
        }
        #pragma unroll
        for (int r = 0; r < 4; ++r) {       // C/D: col=lane&15, row=quad*4+reg
            int row = rt * 16 + quad * 4 + r;
            zu[row * 34 + ctA * 16 + m] = accA[r];
        }
        if (ctA == 0 && m == 0) {
            #pragma unroll
            for (int r = 0; r < 4; ++r) zu[(rt * 16 + quad * 4 + r) * 34 + 32] = acc2[r];
        }
    }
    // ---- phase 2b: per-row sumsq(Z) from bf16 tile (8 threads/row, rotated banks) ----
    {
        int row = t >> 3, sub = t & 7;
        const uint_t* p = (const uint_t*)&zb[row * ZB_STR];
        int rot0 = (sub * 4 + row * 29) & 31;
        float s = 0.f;
        #pragma unroll 8
        for (int j = 0; j < 32; ++j) {
            uint_t w2 = p[sub * 32 + ((j + rot0) & 31)];
            float a = __builtin_bit_cast(float, (uint_t)(w2 << 16));
            float b = __builtin_bit_cast(float, w2 & 0xffff0000u);
            s += a * a + b * b;
        }
        s += __shfl_xor(s, 1); s += __shfl_xor(s, 2); s += __shfl_xor(s, 4);
        if (sub == 0) zu[row * 34 + 33] = s;   // stash ss; solve replaces with ksc
    }
    __syncthreads();

    // ---- phase 3: secant solve (lanes 0..31 of wave 0), coords written into zu in place ----
    if (t < 32) {
        int row = t;
        float ss   = zu[row * 34 + 33];
        float zzmu = zu[row * 34 + 32];
        float mun  = *(const float*)(ws + WS_MUN);
        float Zn2  = ss - 2.f * zzmu + mun;
        float ZUn2 = 0.f;
        #pragma unroll
        for (int k = 0; k < 32; ++k) {
            float zk = zu[row * 34 + k];
            float d1 = zk - xmu_s[k];
            ZUn2 += d1 * d1;
            zu[row * 34 + k] = zk - xcu_s[k];   // coord
        }
        float c  = Zn2 - ZUn2;
        float eg = __expf(-GAMMA * ZUn2);
        float xm2 = c * GUESS, xm1 = c;
        float t1v = 1.f - ALPHA * eg * __expf(-GAMMA * xm1);
        float f1 = t1v * t1v * xm1 - c;
        float t2v = 1.f - ALPHA * eg * __expf(-GAMMA * xm2);
        float f2 = t2v * t2v * xm2 - c;
        for (int it = 0; it < 100; ++it) {
            float fd = f1 - f2;
            if (fabsf(fd) < TOLR) fd = (fd >= 0.f) ? TOLR : -TOLR;
            float xn = xm1 - f1 * (xm1 - xm2) / fd;
            float step = fabsf(xn - xm1);
            xm2 = xm1; f2 = f1; xm1 = xn;
            float tn = 1.f - ALPHA * eg * __expf(-GAMMA * xm1);
            f1 = tn * tn * xm1 - c;
            if (step < TOLR) break;
        }
        zu[row * 34 + 33] = ALPHA * __expf(-GAMMA * (ZUn2 + xm1));  // ksc
    }
    __syncthreads();

    // ---- phase 4: build H tile (overwrites zb region) ----
    {
        int row = t >> 3, sub = t & 7;
        const float* crow = &zu[row * 34];
        int p0 = sub * 68;
        ushort_t ab = ((const ushort_t*)(ws + WS_IU))[p0];
        int a = ab >> 8, b = ab & 255;
        float ca = crow[a];
        for (int pp = p0; pp < p0 + 68; pp += 2) {
            float v0 = 0.f, v1 = 0.f;
            if (pp < NPAIR)     { v0 = ca * crow[b]; if (++b >= 32) { ++a; ca = crow[a & 31]; b = a; } }
            if (pp + 1 < NPAIR) { v1 = ca * crow[b]; if (++b >= 32) { ++a; ca = crow[a & 31]; b = a; } }
            *(uint_t*)&hb[row * HB_STR + pp] = (uint_t)f2bf(v0) | ((uint_t)f2bf(v1) << 16);
        }
    }
    __syncthreads();

    // ---- phase 5: H @ V^T (wave w: cols w*128..+127, 2 row-tiles x 8 col-tiles) + epilogue ----
    {
        const ushort_t* Vb2 = (const ushort_t*)(ws + WS_VB);
        int colT0 = wv * 8;
        f32x4 acc[2][8];
        #pragma unroll
        for (int i = 0; i < 2; ++i)
            #pragma unroll
            for (int j = 0; j < 8; ++j) acc[i][j] = (f32x4){0, 0, 0, 0};

        #pragma unroll
        for (int ks = 0; ks < 17; ++ks) {
            s16x8 b[8];
            #pragma unroll
            for (int ct = 0; ct < 8; ++ct)
                b[ct] = *(const s16x8*)&Vb2[((colT0 + ct) * 17 + ks) * 512 + laneoff];
            s16x8 a0 = *(const s16x8*)&hb[m * HB_STR + ks * 32 + quad * 8];
            s16x8 a1 = *(const s16x8*)&hb[(16 + m) * HB_STR + ks * 32 + quad * 8];
            #pragma unroll
            for (int ct = 0; ct < 8; ++ct) {
                acc[0][ct] = __builtin_amdgcn_mfma_f32_16x16x32_bf16(a0, b[ct], acc[0][ct], 0, 0, 0);
                acc[1][ct] = __builtin_amdgcn_mfma_f32_16x16x32_bf16(a1, b[ct], acc[1][ct], 0, 0, 0);
            }
        }

        // epilogue: out = Z + ksc*(change + corr), Z loads batched 8-deep per col-tile
        const float* chg = (const float*)(ws + WS_CHANGE);
        float kv[2][4]; int zr[2][4];
        #pragma unroll
        for (int rt = 0; rt < 2; ++rt)
            #pragma unroll
            for (int r = 0; r < 4; ++r) {
                int row = rt * 16 + quad * 4 + r;
                kv[rt][r] = zu[row * 34 + 33];
                zr[rt][r] = cidx[row];
            }
        #pragma unroll
        for (int ct = 0; ct < 8; ++ct) {
            int d = wv * 128 + ct * 16 + m;
            float chd = chg[d];
            float zv[8];
            #pragma unroll
            for (int rt = 0; rt < 2; ++rt)
                #pragma unroll
                for (int r = 0; r < 4; ++r)
                    zv[rt * 4 + r] = Z[(size_t)zr[rt][r] * DDIM + d];
            #pragma unroll
            for (int rt = 0; rt < 2; ++rt)
                #pragma unroll
                for (int r = 0; r < 4; ++r)
                    out[(size_t)zr[rt][r] * DDIM + d] =
                        zv[rt * 4 + r] + kv[rt][r] * (chd + acc[rt][ct][r]);
        }
    }
}

extern "C" void kernel_launch(void* const* d_in, const int* in_sizes, int n_in,
                              void* d_out, int out_size, void* d_ws, size_t ws_size,
                              hipStream_t stream) {
    const float* Z   = (const float*)d_in[0];
    const float* U   = (const float*)d_in[1];
    const float* V   = (const float*)d_in[2];
    const float* zmu = (const float*)d_in[3];
    const float* xc  = (const float*)d_in[4];
    const int*   ci  = (const int*)d_in[5];
    char* ws = (char*)d_ws;
    float* out = (float*)d_out;

    hipLaunchKernelGGL(kernelA, dim3(129), dim3(256), 0, stream, U, V, zmu, xc, ws);
    hipLaunchKernelGGL(kernelF, dim3(NBLK), dim3(256), 0, stream, Z, ci, (const char*)ws, out);
}